// Round 4
// baseline (283.487 us; speedup 1.0000x reference)
//
#include <hip/hip_runtime.h>
#include <hip/hip_bf16.h>
#include <math.h>

#define NROW 8192
#define DDIM 256
#define BM 128
#define BN 128
#define BK 64
#define NT_SYM 2080    // 64*65/2 lower-triangular 128x128 tiles
#define NT_FULL 4096

typedef __attribute__((ext_vector_type(8))) short bf16x8;
typedef __attribute__((ext_vector_type(4))) float f32x4;
typedef __attribute__((address_space(3))) unsigned int lds_u32;
typedef const __attribute__((address_space(1))) unsigned int glb_u32;

static __device__ inline unsigned short f2bf(float x) {
    union { float f; unsigned int u; } v; v.f = x;
    unsigned int r = v.u + 0x7fffu + ((v.u >> 16) & 1u);  // RNE
    return (unsigned short)(r >> 16);
}

// DPP row_ror butterfly add: after ror 1,2,4,8 every lane of each 16-lane row
// holds the row sum. VALU pipe only — no DS traffic (vs __shfl_xor/ds_swizzle).
template <int CTRL>
static __device__ inline float dpp_ror_add(float v) {
    int s = __float_as_int(v);
    int r = __builtin_amdgcn_update_dpp(0, s, CTRL, 0xF, 0xF, true);
    return v + __int_as_float(r);
}
static __device__ inline float row16_sum(float v) {
    v = dpp_ror_add<0x121>(v);   // row_ror:1
    v = dpp_ror_add<0x122>(v);   // row_ror:2
    v = dpp_ror_add<0x124>(v);   // row_ror:4
    v = dpp_ror_add<0x128>(v);   // row_ror:8
    return v;
}

// One wave per row: L2-normalize H1/H2 rows, scale by sqrt(2*log2(e)) so the
// bf16 Gram entries come out as 2*log2(e)*s  ->  exp(2s) == exp2(acc).
// diag[row] = 2*dot(z1n,z2n) fp32 (unscaled). Zero-inits rowsums and out.
__global__ __launch_bounds__(256) void normalize_kernel(
        const float* __restrict__ h1, const float* __restrict__ h2,
        unsigned short* __restrict__ z1b, unsigned short* __restrict__ z2b,
        float* __restrict__ diag,
        float* __restrict__ rs1, float* __restrict__ rs2,
        float* __restrict__ rbr, float* __restrict__ rbc,
        float* __restrict__ out) {
    int wave = threadIdx.x >> 6;
    int lane = threadIdx.x & 63;
    int row  = blockIdx.x * 4 + wave;
    if (blockIdx.x == 0 && threadIdx.x == 0) out[0] = 0.f;
    const float4* p1 = (const float4*)(h1 + (size_t)row * DDIM);
    const float4* p2 = (const float4*)(h2 + (size_t)row * DDIM);
    float4 a = p1[lane];
    float4 b = p2[lane];
    float s1 = a.x*a.x + a.y*a.y + a.z*a.z + a.w*a.w;
    float s2 = b.x*b.x + b.y*b.y + b.z*b.z + b.w*b.w;
    #pragma unroll
    for (int m = 1; m < 64; m <<= 1) { s1 += __shfl_xor(s1, m); s2 += __shfl_xor(s2, m); }
    float r1 = 1.0f / fmaxf(sqrtf(s1), 1e-12f);
    float r2 = 1.0f / fmaxf(sqrtf(s2), 1e-12f);
    float n1x = a.x*r1, n1y = a.y*r1, n1z = a.z*r1, n1w = a.w*r1;
    float n2x = b.x*r2, n2y = b.y*r2, n2z = b.z*r2, n2w = b.w*r2;
    float dt = n1x*n2x + n1y*n2y + n1z*n2z + n1w*n2w;
    #pragma unroll
    for (int m = 1; m < 64; m <<= 1) dt += __shfl_xor(dt, m);
    if (lane == 0) {
        diag[row] = 2.0f * dt;
        rs1[row] = 0.f; rs2[row] = 0.f; rbr[row] = 0.f; rbc[row] = 0.f;
    }
    const float SC = 1.69864364f;   // sqrt(2 * log2(e))
    ushort4 o1, o2;
    o1.x = f2bf(n1x*SC); o1.y = f2bf(n1y*SC); o1.z = f2bf(n1z*SC); o1.w = f2bf(n1w*SC);
    o2.x = f2bf(n2x*SC); o2.y = f2bf(n2y*SC); o2.z = f2bf(n2z*SC); o2.w = f2bf(n2w*SC);
    ((ushort4*)(z1b + (size_t)row * DDIM))[lane] = o1;
    ((ushort4*)(z2b + (size_t)row * DDIM))[lane] = o2;
}

// Tiles: b < 2080 -> S11 lower-tri; < 4160 -> S22 lower-tri; else S12 full.
// Symmetric matrices: off-diagonal tile adds rowpart to rowsum[rows] AND
// colpart to rowsum[cols] (same array). Staging via global_load_lds width=16
// into an unpadded 128B-row LDS tile with XOR chunk swizzle (slot = chunk^(row&7))
// on the global-address side -> conflict-free ds_read_b128 fragments.
// Single 32 KB buffer (R3 showed dbuf's occupancy loss > stall win).
__global__ __launch_bounds__(256, 5) void expsum_kernel(
        const unsigned short* __restrict__ z1, const unsigned short* __restrict__ z2,
        float* __restrict__ rs1, float* __restrict__ rs2,
        float* __restrict__ rbr, float* __restrict__ rbc) {
    int b = blockIdx.x;
    int kind, t;
    if (b < NT_SYM)            { kind = 0; t = b; }
    else if (b < 2 * NT_SYM)   { kind = 1; t = b - NT_SYM; }
    else                       { kind = 2; t = b - 2 * NT_SYM; }

    int by, bx;
    const unsigned short *Ap, *Bp;
    float *rowsum, *colsum;
    if (kind == 2) {
        by = t >> 6; bx = t & 63;
        Ap = z1; Bp = z2; rowsum = rbr; colsum = rbc;
    } else {
        by = (int)((sqrtf(8.0f * (float)t + 1.0f) - 1.0f) * 0.5f);
        while ((by + 1) * (by + 2) / 2 <= t) ++by;
        while (by * (by + 1) / 2 > t) --by;
        bx = t - by * (by + 1) / 2;          // bx <= by
        const unsigned short* z = (kind == 0) ? z1 : z2;
        Ap = z; Bp = z;
        rowsum = (kind == 0) ? rs1 : rs2;
        colsum = (bx == by) ? nullptr : rowsum;
    }

    const int rt = by * BM;
    const int ct = bx * BN;

    __shared__ __align__(16) unsigned short lA[BM * BK];  // 16 KB
    __shared__ __align__(16) unsigned short lB[BN * BK];  // 16 KB

    const int tid  = threadIdx.x;
    const int lane = tid & 63;
    const int wid  = tid >> 6;
    const int wr   = wid >> 1;
    const int wc   = wid & 1;
    const int quad = lane >> 4;
    const int l15  = lane & 15;

    const int srow   = lane >> 3;
    const int schunk = (lane & 7) ^ srow;     // XOR swizzle on global side
    const int gcol0  = schunk * 8;

    f32x4 acc[4][4];
    #pragma unroll
    for (int mi = 0; mi < 4; ++mi)
        #pragma unroll
        for (int ni = 0; ni < 4; ++ni)
            acc[mi][ni] = (f32x4){0.f, 0.f, 0.f, 0.f};

    for (int kt = 0; kt < DDIM; kt += BK) {
        #pragma unroll
        for (int p = 0; p < 4; ++p) {
            int r0 = (p * 4 + wid) * 8;
            const unsigned short* ga = Ap + (size_t)(rt + r0 + srow) * DDIM + kt + gcol0;
            __builtin_amdgcn_global_load_lds((glb_u32*)ga, (lds_u32*)(lA + r0 * BK), 16, 0, 0);
            const unsigned short* gb = Bp + (size_t)(ct + r0 + srow) * DDIM + kt + gcol0;
            __builtin_amdgcn_global_load_lds((glb_u32*)gb, (lds_u32*)(lB + r0 * BK), 16, 0, 0);
        }
        __syncthreads();
        #pragma unroll
        for (int ks = 0; ks < 2; ++ks) {
            bf16x8 af[4], bfr[4];
            #pragma unroll
            for (int mi = 0; mi < 4; ++mi) {
                int r = wr * 64 + mi * 16 + l15;
                int slot = (ks * 4 + quad) ^ (l15 & 7);
                af[mi] = *((const bf16x8*)(lA + r * BK + slot * 8));
            }
            #pragma unroll
            for (int ni = 0; ni < 4; ++ni) {
                int c = wc * 64 + ni * 16 + l15;
                int slot = (ks * 4 + quad) ^ (l15 & 7);
                bfr[ni] = *((const bf16x8*)(lB + c * BK + slot * 8));
            }
            #pragma unroll
            for (int mi = 0; mi < 4; ++mi)
                #pragma unroll
                for (int ni = 0; ni < 4; ++ni)
                    acc[mi][ni] = __builtin_amdgcn_mfma_f32_16x16x32_bf16(
                        af[mi], bfr[ni], acc[mi][ni], 0, 0, 0);
        }
        __syncthreads();
    }

    // C/D layout: col = lane&15, row = quad*4 + reg. acc = 2*log2e*s -> exp2.
    float colpart[4] = {0.f, 0.f, 0.f, 0.f};
    #pragma unroll
    for (int mi = 0; mi < 4; ++mi) {
        #pragma unroll
        for (int r = 0; r < 4; ++r) {
            float rp = 0.f;
            #pragma unroll
            for (int ni = 0; ni < 4; ++ni) {
                float e = exp2f(acc[mi][ni][r]);
                rp += e;
                colpart[ni] += e;
            }
            rp = row16_sum(rp);          // DPP, VALU-pipe only
            if (l15 == 0) {
                int grow = rt + wr * 64 + mi * 16 + quad * 4 + r;
                atomicAdd(&rowsum[grow], rp);
            }
        }
    }
    if (colsum) {
        #pragma unroll
        for (int ni = 0; ni < 4; ++ni) {
            float cp = colpart[ni];
            cp += __shfl_xor(cp, 16);
            cp += __shfl_xor(cp, 32);
            if (lane < 16) {
                int gcol = ct + wc * 64 + ni * 16 + l15;
                atomicAdd(&colsum[gcol], cp);
            }
        }
    }
}

// 32 blocks x 256 threads, one row each; block-reduce then one atomicAdd.
__global__ __launch_bounds__(256) void finalize_kernel(
        const float* __restrict__ rs1, const float* __restrict__ rs2,
        const float* __restrict__ rbr, const float* __restrict__ rbc,
        const float* __restrict__ diag, float* __restrict__ out) {
    __shared__ float s4[4];
    const float E2 = 7.38905609893065f;   // exp(1/tau), tau=0.5
    int i = blockIdx.x * 256 + threadIdx.x;
    float den1 = rs1[i] + rbr[i] - E2;
    float den2 = rs2[i] + rbc[i] - E2;
    float v = 0.5f * (logf(den1) + logf(den2)) - diag[i];
    #pragma unroll
    for (int m = 1; m < 64; m <<= 1) v += __shfl_xor(v, m);
    if ((threadIdx.x & 63) == 0) s4[threadIdx.x >> 6] = v;
    __syncthreads();
    if (threadIdx.x == 0) {
        float t = (s4[0] + s4[1] + s4[2] + s4[3]) * (1.0f / (float)NROW);
        atomicAdd(out, t);
    }
}

extern "C" void kernel_launch(void* const* d_in, const int* in_sizes, int n_in,
                              void* d_out, int out_size, void* d_ws, size_t ws_size,
                              hipStream_t stream) {
    const float* h1 = (const float*)d_in[0];
    const float* h2 = (const float*)d_in[1];
    float* out = (float*)d_out;

    char* ws = (char*)d_ws;
    unsigned short* z1b = (unsigned short*)ws;                                // 4 MB
    unsigned short* z2b = (unsigned short*)(ws + (size_t)NROW * DDIM * 2);    // 4 MB
    float* sums = (float*)(ws + (size_t)2 * NROW * DDIM * 2);
    float* rs1  = sums;
    float* rs2  = sums + NROW;
    float* rbr  = sums + 2 * NROW;
    float* rbc  = sums + 3 * NROW;
    float* diag = sums + 4 * NROW;

    normalize_kernel<<<NROW / 4, 256, 0, stream>>>(h1, h2, z1b, z2b, diag,
                                                   rs1, rs2, rbr, rbc, out);

    expsum_kernel<<<2 * NT_SYM + NT_FULL, 256, 0, stream>>>(z1b, z2b, rs1, rs2, rbr, rbc);

    finalize_kernel<<<NROW / 256, 256, 0, stream>>>(rs1, rs2, rbr, rbc, diag, out);
}

// Round 5
// 169.094 us; speedup vs baseline: 1.6765x; 1.6765x over previous
//
#include <hip/hip_runtime.h>
#include <hip/hip_bf16.h>
#include <math.h>

#define NROW 8192
#define DDIM 256
#define BM 128
#define BN 128
#define BK 128          // fp8: full 128-elem k-tile = 128 B rows, 2 k-iterations
#define NT_SYM 2080     // 64*65/2 lower-triangular 128x128 tiles
#define NT_FULL 4096

typedef __attribute__((ext_vector_type(4))) float f32x4;
typedef __attribute__((address_space(3))) unsigned int lds_u32;
typedef const __attribute__((address_space(1))) unsigned int glb_u32;

// DPP row_ror butterfly add: after ror 1,2,4,8 every lane of each 16-lane row
// holds the row sum. VALU pipe only — no DS traffic.
template <int CTRL>
static __device__ inline float dpp_ror_add(float v) {
    int s = __float_as_int(v);
    int r = __builtin_amdgcn_update_dpp(0, s, CTRL, 0xF, 0xF, true);
    return v + __int_as_float(r);
}
static __device__ inline float row16_sum(float v) {
    v = dpp_ror_add<0x121>(v);
    v = dpp_ror_add<0x122>(v);
    v = dpp_ror_add<0x124>(v);
    v = dpp_ror_add<0x128>(v);
    return v;
}

// Pack 4 floats -> 4 fp8 e4m3 bytes (HW cvt, OCP on gfx950 — self-consistent
// with the fp8 MFMA's decode).
static __device__ inline unsigned int pack_fp8x4(float a, float b, float c, float d) {
    int p = __builtin_amdgcn_cvt_pk_fp8_f32(a, b, 0, false);
    p = __builtin_amdgcn_cvt_pk_fp8_f32(c, d, p, true);
    return (unsigned int)p;
}

// One wave per row: L2-normalize H1/H2 rows, scale by sqrt(2*log2(e)) so the
// fp8 Gram entries come out as 2*log2(e)*s -> exp(2s) == exp2(acc).
// diag[row] = 2*dot(z1n,z2n) fp32 (exact). Zero-inits rowsums and out.
__global__ __launch_bounds__(256) void normalize_kernel(
        const float* __restrict__ h1, const float* __restrict__ h2,
        unsigned char* __restrict__ z1b, unsigned char* __restrict__ z2b,
        float* __restrict__ diag,
        float* __restrict__ rs1, float* __restrict__ rs2,
        float* __restrict__ rbr, float* __restrict__ rbc,
        float* __restrict__ out) {
    int wave = threadIdx.x >> 6;
    int lane = threadIdx.x & 63;
    int row  = blockIdx.x * 4 + wave;
    if (blockIdx.x == 0 && threadIdx.x == 0) out[0] = 0.f;
    const float4* p1 = (const float4*)(h1 + (size_t)row * DDIM);
    const float4* p2 = (const float4*)(h2 + (size_t)row * DDIM);
    float4 a = p1[lane];
    float4 b = p2[lane];
    float s1 = a.x*a.x + a.y*a.y + a.z*a.z + a.w*a.w;
    float s2 = b.x*b.x + b.y*b.y + b.z*b.z + b.w*b.w;
    #pragma unroll
    for (int m = 1; m < 64; m <<= 1) { s1 += __shfl_xor(s1, m); s2 += __shfl_xor(s2, m); }
    float r1 = 1.0f / fmaxf(sqrtf(s1), 1e-12f);
    float r2 = 1.0f / fmaxf(sqrtf(s2), 1e-12f);
    float n1x = a.x*r1, n1y = a.y*r1, n1z = a.z*r1, n1w = a.w*r1;
    float n2x = b.x*r2, n2y = b.y*r2, n2z = b.z*r2, n2w = b.w*r2;
    float dt = n1x*n2x + n1y*n2y + n1z*n2z + n1w*n2w;
    #pragma unroll
    for (int m = 1; m < 64; m <<= 1) dt += __shfl_xor(dt, m);
    if (lane == 0) {
        diag[row] = 2.0f * dt;
        rs1[row] = 0.f; rs2[row] = 0.f; rbr[row] = 0.f; rbc[row] = 0.f;
    }
    const float SC = 1.69864364f;   // sqrt(2 * log2(e))
    ((unsigned int*)(z1b + (size_t)row * DDIM))[lane] =
        pack_fp8x4(n1x*SC, n1y*SC, n1z*SC, n1w*SC);
    ((unsigned int*)(z2b + (size_t)row * DDIM))[lane] =
        pack_fp8x4(n2x*SC, n2y*SC, n2z*SC, n2w*SC);
}

// Tiles: b < 2080 -> S11 lower-tri; < 4160 -> S22 lower-tri; else S12 full.
// fp8 e4m3 Gram via mfma_f32_16x16x32_fp8_fp8, BK=128 (2 k-iterations -> half
// the barrier drains of R2). LDS rows are 128 B = 8 16B-granules; granule g of
// row r stored at physical slot g ^ ((r>>1)&7) (swizzle applied on the global
// address side of the DMA; 2-row pairing keeps the 16B DMA unit intact and
// costs only a free 2-way conflict). ds_read_b64 fragments land balanced
// (4 cyc = b64 minimum). Single buffer, (256,4) — R3/R4 showed dbuf and
// forced-occupancy both lose.
__global__ __launch_bounds__(256, 4) void expsum_kernel(
        const unsigned char* __restrict__ z1, const unsigned char* __restrict__ z2,
        float* __restrict__ rs1, float* __restrict__ rs2,
        float* __restrict__ rbr, float* __restrict__ rbc) {
    int b = blockIdx.x;
    int kind, t;
    if (b < NT_SYM)            { kind = 0; t = b; }
    else if (b < 2 * NT_SYM)   { kind = 1; t = b - NT_SYM; }
    else                       { kind = 2; t = b - 2 * NT_SYM; }

    int by, bx;
    const unsigned char *Ap, *Bp;
    float *rowsum, *colsum;
    if (kind == 2) {
        by = t >> 6; bx = t & 63;
        Ap = z1; Bp = z2; rowsum = rbr; colsum = rbc;
    } else {
        by = (int)((sqrtf(8.0f * (float)t + 1.0f) - 1.0f) * 0.5f);
        while ((by + 1) * (by + 2) / 2 <= t) ++by;
        while (by * (by + 1) / 2 > t) --by;
        bx = t - by * (by + 1) / 2;          // bx <= by
        const unsigned char* z = (kind == 0) ? z1 : z2;
        Ap = z; Bp = z;
        rowsum = (kind == 0) ? rs1 : rs2;
        colsum = (bx == by) ? nullptr : rowsum;
    }

    const int rt = by * BM;
    const int ct = bx * BN;

    __shared__ __align__(16) unsigned char lA[BM * BK];  // 16 KB
    __shared__ __align__(16) unsigned char lB[BN * BK];  // 16 KB

    const int tid  = threadIdx.x;
    const int lane = tid & 63;
    const int wid  = tid >> 6;
    const int wr   = wid >> 1;
    const int wc   = wid & 1;
    const int quad = lane >> 4;
    const int l15  = lane & 15;

    // DMA lane mapping: 8 lanes per 128-B row, 8 rows per wave-instruction.
    const int srow = lane >> 3;           // row within 8-row group
    const int sgt  = lane & 7;            // physical 16B granule (= DMA slot)

    f32x4 acc[4][4];
    #pragma unroll
    for (int mi = 0; mi < 4; ++mi)
        #pragma unroll
        for (int ni = 0; ni < 4; ++ni)
            acc[mi][ni] = (f32x4){0.f, 0.f, 0.f, 0.f};

    for (int kt = 0; kt < DDIM; kt += BK) {
        // Stage A and B 128x128B fp8 tiles: 16 wave-DMAs per tile, split
        // across 4 waves -> 4 per wave per tile, 16 B/lane.
        #pragma unroll
        for (int p = 0; p < 4; ++p) {
            int r0 = (p * 4 + wid) * 8;
            int r  = r0 + srow;
            int gg = sgt ^ ((r >> 1) & 7);          // global granule to fetch
            const unsigned char* ga = Ap + (size_t)(rt + r) * DDIM + kt + gg * 16;
            __builtin_amdgcn_global_load_lds((glb_u32*)ga, (lds_u32*)(lA + r0 * BK), 16, 0, 0);
            const unsigned char* gb = Bp + (size_t)(ct + r) * DDIM + kt + gg * 16;
            __builtin_amdgcn_global_load_lds((glb_u32*)gb, (lds_u32*)(lB + r0 * BK), 16, 0, 0);
        }
        __syncthreads();
        #pragma unroll
        for (int ks = 0; ks < 4; ++ks) {            // 4 x K=32
            long af[4], bfr[4];
            const int g    = ks * 2 + (quad >> 1);  // logical 16B granule
            const int half = (quad & 1) * 8;        // 8-B half within granule
            #pragma unroll
            for (int mi = 0; mi < 4; ++mi) {
                int r = wr * 64 + mi * 16 + l15;
                int phys = (g ^ ((r >> 1) & 7)) * 16 + half;
                af[mi] = *((const long*)(lA + r * BK + phys));
            }
            #pragma unroll
            for (int ni = 0; ni < 4; ++ni) {
                int c = wc * 64 + ni * 16 + l15;
                int phys = (g ^ ((c >> 1) & 7)) * 16 + half;
                bfr[ni] = *((const long*)(lB + c * BK + phys));
            }
            #pragma unroll
            for (int mi = 0; mi < 4; ++mi)
                #pragma unroll
                for (int ni = 0; ni < 4; ++ni)
                    acc[mi][ni] = __builtin_amdgcn_mfma_f32_16x16x32_fp8_fp8(
                        af[mi], bfr[ni], acc[mi][ni], 0, 0, 0);
        }
        __syncthreads();
    }

    // C/D layout: col = lane&15, row = quad*4 + reg. acc = 2*log2e*s -> exp2.
    float colpart[4] = {0.f, 0.f, 0.f, 0.f};
    #pragma unroll
    for (int mi = 0; mi < 4; ++mi) {
        #pragma unroll
        for (int r = 0; r < 4; ++r) {
            float rp = 0.f;
            #pragma unroll
            for (int ni = 0; ni < 4; ++ni) {
                float e = exp2f(acc[mi][ni][r]);
                rp += e;
                colpart[ni] += e;
            }
            rp = row16_sum(rp);          // DPP, VALU-pipe only
            if (l15 == 0) {
                int grow = rt + wr * 64 + mi * 16 + quad * 4 + r;
                atomicAdd(&rowsum[grow], rp);
            }
        }
    }
    if (colsum) {
        #pragma unroll
        for (int ni = 0; ni < 4; ++ni) {
            float cp = colpart[ni];
            cp += __shfl_xor(cp, 16);
            cp += __shfl_xor(cp, 32);
            if (lane < 16) {
                int gcol = ct + wc * 64 + ni * 16 + l15;
                atomicAdd(&colsum[gcol], cp);
            }
        }
    }
}

// 32 blocks x 256 threads, one row each; block-reduce then one atomicAdd.
__global__ __launch_bounds__(256) void finalize_kernel(
        const float* __restrict__ rs1, const float* __restrict__ rs2,
        const float* __restrict__ rbr, const float* __restrict__ rbc,
        const float* __restrict__ diag, float* __restrict__ out) {
    __shared__ float s4[4];
    const float E2 = 7.38905609893065f;   // exp(1/tau), tau=0.5
    int i = blockIdx.x * 256 + threadIdx.x;
    float den1 = rs1[i] + rbr[i] - E2;
    float den2 = rs2[i] + rbc[i] - E2;
    float v = 0.5f * (logf(den1) + logf(den2)) - diag[i];
    #pragma unroll
    for (int m = 1; m < 64; m <<= 1) v += __shfl_xor(v, m);
    if ((threadIdx.x & 63) == 0) s4[threadIdx.x >> 6] = v;
    __syncthreads();
    if (threadIdx.x == 0) {
        float t = (s4[0] + s4[1] + s4[2] + s4[3]) * (1.0f / (float)NROW);
        atomicAdd(out, t);
    }
}

extern "C" void kernel_launch(void* const* d_in, const int* in_sizes, int n_in,
                              void* d_out, int out_size, void* d_ws, size_t ws_size,
                              hipStream_t stream) {
    const float* h1 = (const float*)d_in[0];
    const float* h2 = (const float*)d_in[1];
    float* out = (float*)d_out;

    char* ws = (char*)d_ws;
    unsigned char* z1b = (unsigned char*)ws;                             // 2 MB
    unsigned char* z2b = (unsigned char*)(ws + (size_t)NROW * DDIM);     // 2 MB
    float* sums = (float*)(ws + (size_t)2 * NROW * DDIM);
    float* rs1  = sums;
    float* rs2  = sums + NROW;
    float* rbr  = sums + 2 * NROW;
    float* rbc  = sums + 3 * NROW;
    float* diag = sums + 4 * NROW;

    normalize_kernel<<<NROW / 4, 256, 0, stream>>>(h1, h2, z1b, z2b, diag,
                                                   rs1, rs2, rbr, rbc, out);

    expsum_kernel<<<2 * NT_SYM + NT_FULL, 256, 0, stream>>>(z1b, z2b, rs1, rs2, rbr, rbc);

    finalize_kernel<<<NROW / 256, 256, 0, stream>>>(rs1, rs2, rbr, rbc, diag, out);
}